// Round 1
// baseline (289.249 us; speedup 1.0000x reference)
//
#include <hip/hip_runtime.h>

// BasicNCA: 16 sequential steps of (11x11 SAME conv -> per-pixel MLP 1->10->10->1
// -> residual add -> clip[0,1]) on (16,1,256,256) fp32.
// Output = all 17 states concatenated: out[t] slab, t=0..16, slab = 16*256*256 floats.
// Step k reads slab k, writes slab k+1 (stream ordering provides the device-wide sync).

#define HH 256
#define WW 256
#define BB 16
#define TH 16
#define TW 64
#define SH (TH + 10)   // 26
#define SW (TW + 10)   // 74
#define SWP 76         // padded stride, multiple of 4 floats -> 16B-aligned rows
#define SLAB (BB * HH * WW)  // 1048576 floats per state

__global__ __launch_bounds__(256) void nca_copy_x(const float* __restrict__ x,
                                                  float* __restrict__ out) {
    int i = (blockIdx.x * 256 + threadIdx.x) * 4;
    *(float4*)(out + i) = *(const float4*)(x + i);
}

__global__ __launch_bounds__(256) void nca_step(
    const float* __restrict__ src, float* __restrict__ dst,
    const float* __restrict__ Kk,
    const float* __restrict__ w1, const float* __restrict__ b1,
    const float* __restrict__ w2, const float* __restrict__ b2,
    const float* __restrict__ w3, const float* __restrict__ b3) {
    __shared__ __align__(16) float s[SH * SWP];

    const int tid = threadIdx.x;
    const int b   = blockIdx.z;
    const int gy0 = blockIdx.y * TH;
    const int gx0 = blockIdx.x * TW;
    const float* img = src + b * HH * WW;

    // ---- stage halo'd tile (zero pad = SAME padding) ----
    for (int i = tid; i < SH * SW; i += 256) {
        int r = i / SW, c = i - r * SW;
        int gy = gy0 - 5 + r, gx = gx0 - 5 + c;
        float v = 0.f;
        if (gy >= 0 && gy < HH && gx >= 0 && gx < WW) v = img[gy * WW + gx];
        s[r * SWP + c] = v;
    }
    __syncthreads();

    const int tx = tid & 15, ty = tid >> 4;
    const int x0 = tx * 4;  // 4 consecutive output pixels per thread

    // ---- 11x11 conv via 14-wide register sliding window per ky ----
    float acc0 = 0.f, acc1 = 0.f, acc2 = 0.f, acc3 = 0.f;
#pragma unroll
    for (int ky = 0; ky < 11; ++ky) {
        const float* row = &s[(ty + ky) * SWP + x0];
        float win[16];
        *(float4*)(win + 0)  = *(const float4*)(row + 0);
        *(float4*)(win + 4)  = *(const float4*)(row + 4);
        *(float4*)(win + 8)  = *(const float4*)(row + 8);
        *(float2*)(win + 12) = *(const float2*)(row + 12);
#pragma unroll
        for (int kx = 0; kx < 11; ++kx) {
            float kv = Kk[ky * 11 + kx];  // wave-uniform -> s_load
            acc0 = fmaf(win[kx + 0], kv, acc0);
            acc1 = fmaf(win[kx + 1], kv, acc1);
            acc2 = fmaf(win[kx + 2], kv, acc2);
            acc3 = fmaf(win[kx + 3], kv, acc3);
        }
    }

    // ---- per-pixel MLP 1->10->10->1, residual, clip ----
    const float b3v = b3[0];
    float vacc[4] = {acc0, acc1, acc2, acc3};
    float res[4];
#pragma unroll
    for (int p = 0; p < 4; ++p) {
        float v = vacc[p];
        float h1[10];
#pragma unroll
        for (int i = 0; i < 10; ++i)
            h1[i] = fmaxf(fmaf(v, w1[i], b1[i]), 0.f);
        float y = b3v;
#pragma unroll
        for (int o = 0; o < 10; ++o) {
            float a = b2[o];
#pragma unroll
            for (int i = 0; i < 10; ++i)
                a = fmaf(h1[i], w2[o * 10 + i], a);
            y = fmaf(fmaxf(a, 0.f), w3[o], y);
        }
        float xc = s[(ty + 5) * SWP + x0 + 5 + p];
        res[p] = fminf(fmaxf(xc + y, 0.f), 1.f);
    }

    float* orow = dst + b * HH * WW + (gy0 + ty) * WW + gx0 + x0;
    *(float4*)orow = make_float4(res[0], res[1], res[2], res[3]);
}

extern "C" void kernel_launch(void* const* d_in, const int* in_sizes, int n_in,
                              void* d_out, int out_size, void* d_ws, size_t ws_size,
                              hipStream_t stream) {
    const float* x  = (const float*)d_in[0];
    const float* Kk = (const float*)d_in[1];
    const float* w1 = (const float*)d_in[2];
    const float* b1 = (const float*)d_in[3];
    const float* w2 = (const float*)d_in[4];
    const float* b2 = (const float*)d_in[5];
    const float* w3 = (const float*)d_in[6];
    const float* b3 = (const float*)d_in[7];
    float* out = (float*)d_out;

    // t=0 slab is the input itself
    nca_copy_x<<<SLAB / (256 * 4), 256, 0, stream>>>(x, out);

    // 16 steps, chained through the output buffer (steps fixed at 16 per setup_inputs)
    dim3 grid(WW / TW, HH / TH, BB);
    for (int k = 0; k < 16; ++k) {
        nca_step<<<grid, 256, 0, stream>>>(out + (size_t)k * SLAB,
                                           out + (size_t)(k + 1) * SLAB,
                                           Kk, w1, b1, w2, b2, w3, b3);
    }
}